// Round 1
// 68.887 us; speedup vs baseline: 1.0461x; 1.0461x over previous
//
#include <hip/hip_runtime.h>

// SU2 attention, MI355X — round 5: occupancy + packed-fp32.
// Math: logits.real = dot4(q_hat, k_hat); |x*SCALE| <= 0.7071 so softmax
// needs NO max-subtraction -> partials combine by plain sum.
// Per-head table (raw spinor float4 + inv-norm) staged in LDS (40 KB).
// Round-5 changes vs round-4:
//  * block = 512 threads (8 waves), QR = 4  -> 4096 waves total
//    = 4 waves/SIMD (was 2): 2x latency hiding for LDS/exp bubbles.
//    LDS still 40 KB -> 2 blocks/CU, grid unchanged at (64, 8).
//  * inner math on ext_vector float2 + __builtin_elementwise_fma so the
//    backend emits v_pk_fma_f32 / v_pk_mul_f32 (gfx90a+ packed fp32):
//    12 -> ~8 issue slots per (i,j) element.
// Output PLANAR: d_out = [32768 reals (i,h,d)], then [32768 imags].

#define S 2048
#define H 8
#define QR 4          // queries per wave (register-tiled)
#define NW 8          // waves per block
#define TPB (NW * 64) // 512 threads

typedef float vf2 __attribute__((ext_vector_type(2)));

__device__ inline float fast_exp2(float x) {
#if __has_builtin(__builtin_amdgcn_exp2f)
    return __builtin_amdgcn_exp2f(x);
#else
    return exp2f(x);
#endif
}

// grid = (64, 8): x = query group (8 waves x 4 q = 32 q/block), y = head.
__global__ __launch_bounds__(TPB, 4) void su2_attn_fused(
        const float* __restrict__ re, const float* __restrict__ im,
        float2* __restrict__ outr, float2* __restrict__ outi) {
    __shared__ float4 vt[S];   // raw spinor (re0, im0, re1, im1), 32 KB
    __shared__ float  nt[S];   // 1/||spinor||, 8 KB

    const int h    = blockIdx.y;
    const int lane = threadIdx.x & 63;
    const int wave = threadIdx.x >> 6;
    const int i_base = (blockIdx.x * NW + wave) * QR;

    // ---- stage this head's table into LDS (strided 8B loads, L2-resident)
    const float2* __restrict__ re2 = (const float2*)re;  // input (j, h, d)
    const float2* __restrict__ im2 = (const float2*)im;
#pragma unroll
    for (int k = 0; k < S / TPB; ++k) {
        int j = k * TPB + threadIdx.x;
        float2 r = re2[j * H + h];
        float2 m = im2[j * H + h];
        float ss = r.x * r.x + m.x * m.x + r.y * r.y + m.y * m.y;
        vt[j] = make_float4(r.x, m.x, r.y, m.y);
        nt[j] = rsqrtf(ss);
    }
    __syncthreads();

    // ---- query fragments with SCALE*log2(e)*inv_norm folded in
    const float c = 0.70710678118654752440f * 1.44269504088896340736f;
    vf2 qc0[QR], qc1[QR];
#pragma unroll
    for (int r = 0; r < QR; ++r) {
        float4 v = vt[i_base + r];              // LDS broadcast
        float  s = nt[i_base + r] * c;
        vf2 q0 = {v.x * s, v.y * s};
        vf2 q1 = {v.z * s, v.w * s};
        qc0[r] = q0;
        qc1[r] = q1;
    }

    float l[QR];
    vf2 a0[QR], a1[QR];
#pragma unroll
    for (int r = 0; r < QR; ++r) {
        l[r]  = 0.f;
        a0[r] = (vf2){0.f, 0.f};
        a1[r] = (vf2){0.f, 0.f};
    }

    // ---- main loop: j split over 64 lanes, 32 iters
#pragma unroll 4
    for (int jj = 0; jj < S / 64; ++jj) {
        int j = jj * 64 + lane;
        float4 v   = vt[j];                     // ds_read_b128, conflict-free
        float  inv = nt[j];
        vf2 v0 = {v.x, v.y};
        vf2 v1 = {v.z, v.w};
#pragma unroll
        for (int r = 0; r < QR; ++r) {
            vf2 d2 = __builtin_elementwise_fma(qc1[r], v1, qc0[r] * v0);
            float p = fast_exp2((d2.x + d2.y) * inv);
            l[r] += p;
            vf2 pp = {p, p};
            a0[r] = __builtin_elementwise_fma(pp, v0, a0[r]);
            a1[r] = __builtin_elementwise_fma(pp, v1, a1[r]);
        }
    }

    // ---- butterfly sum all-reduce across 64 lanes (plain sums)
#pragma unroll
    for (int r = 0; r < QR; ++r) {
#pragma unroll
        for (int m = 32; m >= 1; m >>= 1) {
            l[r]    += __shfl_xor(l[r], m, 64);
            a0[r].x += __shfl_xor(a0[r].x, m, 64);
            a0[r].y += __shfl_xor(a0[r].y, m, 64);
            a1[r].x += __shfl_xor(a1[r].x, m, 64);
            a1[r].y += __shfl_xor(a1[r].y, m, 64);
        }
    }

    if (lane == 0) {
#pragma unroll
        for (int r = 0; r < QR; ++r) {
            float invl = 1.0f / l[r];
            int i = i_base + r;
            // planar: real plane then imag plane, each (i, h, d) as float2
            outr[i * H + h] = make_float2(a0[r].x * invl, a1[r].x * invl);
            outi[i * H + h] = make_float2(a0[r].y * invl, a1[r].y * invl);
        }
    }
}

extern "C" void kernel_launch(void* const* d_in, const int* in_sizes, int n_in,
                              void* d_out, int out_size, void* d_ws, size_t ws_size,
                              hipStream_t stream) {
    const float* re = (const float*)d_in[0];
    const float* im = (const float*)d_in[1];
    float2* outr = (float2*)d_out;    // reals: 16384 float2
    float2* outi = outr + S * H;      // imags
    (void)d_ws; (void)ws_size;

    su2_attn_fused<<<dim3(S / (NW * QR), H), dim3(TPB), 0, stream>>>(re, im, outr, outi);
}